// Round 1
// baseline (99.475 us; speedup 1.0000x reference)
//
#include <hip/hip_runtime.h>

// Problem constants
#define NXC 21
#define NDR 5
#define NFEAT 27          // 1 con + 21 x + 5 drug
#define NTERMS 568        // 1 + 21 + 105 + 210 + 210 + 21
// coefficient table layout (in d_ws):
//  [0]        c0 (constant term)
//  [1..21]    LX[i]  (linear-in-x coeffs)
//  [22..42]   LY[i]  (hill coeffs, applied to y_i = x_i/(0.5+x_i))
//  [43..147]  D[d*21+i] (drug coeffs)
//  [148..567] BM interleaved: pair k (lexicographic i<j): [148+2k]=bilin, [148+2k+1]=mm2
#define OFF_LX 1
#define OFF_LY 22
#define OFF_D  43
#define OFF_BM 148
#define NCOEF  568

__global__ void sindy_prep(const float* __restrict__ a,
                           const int* __restrict__ lin_idx,
                           const int* __restrict__ drug_idx,
                           const int* __restrict__ bilin_idx,
                           const int* __restrict__ mm2_idx,
                           const int* __restrict__ hill_idx,
                           const void* __restrict__ uses_self,
                           float* __restrict__ cfs) {
    __shared__ int s_mode;
    const int tid = threadIdx.x;
    if (tid == 0) {
        // Detect uses_self storage: 0 = int32 {0,1}, 1 = byte, 2 = float32
        int mode = 0;
        const int* u32 = (const int*)uses_self;
        for (int j = 0; j < NTERMS / 4; ++j) {   // stay within 568 bytes worst case
            int v = u32[j];
            if (v == 0 || v == 1) continue;
            mode = (v == 0x3f800000) ? 2 : 1;
            break;
        }
        s_mode = mode;
    }
    // zero table (safety; every slot is also written below for this library)
    for (int k = tid; k < NCOEF; k += blockDim.x) cfs[k] = 0.f;
    __syncthreads();
    const int mode = s_mode;

    for (int j = tid; j < NTERMS; j += blockDim.x) {
        float av = a[j];
        bool us;
        if (mode == 0)      us = ((const int*)uses_self)[j] != 0;
        else if (mode == 1) us = ((const unsigned char*)uses_self)[j] != 0;
        else                us = ((const float*)uses_self)[j] != 0.f;
        bool zc = (us ? (av > 0.f) : (av < 0.f)) && (j >= 2);
        float ae = zc ? 0.f : av;

        if (j == 0) {
            cfs[0] = ae;
        } else if (j < 22) {                       // linear
            int k = j - 1;
            cfs[OFF_LX + lin_idx[k]] = ae;
        } else if (j < 127) {                      // drug
            int k = j - 22;
            int xi = drug_idx[2 * k], dj = drug_idx[2 * k + 1];
            cfs[OFF_D + dj * NXC + xi] = ae;
        } else if (j < 337) {                      // bilinear
            int k = j - 127;
            int i0 = bilin_idx[2 * k], i1 = bilin_idx[2 * k + 1];
            int r = 20 * i0 - (i0 * (i0 - 1)) / 2 + (i1 - i0 - 1);
            cfs[OFF_BM + 2 * r] = ae;
        } else if (j < 547) {                      // MM2
            int k = j - 337;
            int i0 = mm2_idx[2 * k], i1 = mm2_idx[2 * k + 1];
            int r = 20 * i0 - (i0 * (i0 - 1)) / 2 + (i1 - i0 - 1);
            cfs[OFF_BM + 2 * r + 1] = ae;
        } else {                                   // hill
            int k = j - 547;
            cfs[OFF_LY + hill_idx[k]] = ae;
        }
    }
}

// 512 points per block, 2 points per thread.
#define PTS_PER_BLOCK 512
#define LDS_F4 ((PTS_PER_BLOCK * NFEAT) / 4)   // 3456 float4 = 55296 B

__global__ __launch_bounds__(256) void sindy_main(const float* __restrict__ cand,
                                                  const float* __restrict__ cfs,
                                                  float* __restrict__ out) {
    __shared__ float sx[PTS_PER_BLOCK * NFEAT];
    const int tid = threadIdx.x;
    const size_t base = (size_t)blockIdx.x * PTS_PER_BLOCK;

    // Coalesced float4 staging of this block's 512 candidate rows
    const float4* g4 = (const float4*)(cand + base * NFEAT);
    float4* s4 = (float4*)sx;
#pragma unroll
    for (int k = 0; k < 14; ++k) {
        int idx = tid + k * 256;
        if (idx < LDS_F4) s4[idx] = g4[idx];
    }
    __syncthreads();

    const float* r0 = sx + tid * NFEAT;           // stride-27: 2-way bank alias = free
    const float* r1 = sx + (tid + 256) * NFEAT;

    float x0[NXC], y0[NXC], x1[NXC], y1[NXC];
    const float c0 = cfs[0];
    float acc0 = c0 * r0[0];
    float acc1 = c0 * r1[0];

#pragma unroll
    for (int i = 0; i < NXC; ++i) {
        x0[i] = r0[1 + i];
        x1[i] = r1[1 + i];
        y0[i] = x0[i] * __builtin_amdgcn_rcpf(0.5f + x0[i]);
        y1[i] = x1[i] * __builtin_amdgcn_rcpf(0.5f + x1[i]);
        float lx = cfs[OFF_LX + i], ly = cfs[OFF_LY + i];
        acc0 += lx * x0[i] + ly * y0[i];
        acc1 += lx * x1[i] + ly * y1[i];
    }

#pragma unroll
    for (int d = 0; d < NDR; ++d) {
        float s0 = 0.f, s1 = 0.f;
#pragma unroll
        for (int i = 0; i < NXC; ++i) {
            float c = cfs[OFF_D + d * NXC + i];
            s0 += c * x0[i];
            s1 += c * x1[i];
        }
        acc0 += r0[1 + NXC + d] * s0;
        acc1 += r1[1 + NXC + d] * s1;
    }

    // bilinear + MM2: grouped by first index i, inner over j>i (pair-lex order)
    int k = 0;
#pragma unroll
    for (int i = 0; i < NXC - 1; ++i) {
        float sB0 = 0.f, sM0 = 0.f, sB1 = 0.f, sM1 = 0.f;
#pragma unroll
        for (int jj = i + 1; jj < NXC; ++jj) {
            float bk = cfs[OFF_BM + 2 * k];
            float mk = cfs[OFF_BM + 2 * k + 1];
            sB0 += bk * x0[jj];
            sM0 += mk * x0[jj];
            sB1 += bk * x1[jj];
            sM1 += mk * x1[jj];
            ++k;
        }
        acc0 += x0[i] * sB0 + y0[i] * sM0;
        acc1 += x1[i] * sB1 + y1[i] * sM1;
    }

    out[base + tid] = acc0;
    out[base + 256 + tid] = acc1;
}

extern "C" void kernel_launch(void* const* d_in, const int* in_sizes, int n_in,
                              void* d_out, int out_size, void* d_ws, size_t ws_size,
                              hipStream_t stream) {
    const float* cand  = (const float*)d_in[0];
    const float* a     = (const float*)d_in[1];
    const int*   lin   = (const int*)d_in[2];
    const int*   drug  = (const int*)d_in[3];
    const int*   bilin = (const int*)d_in[4];
    const int*   mm2   = (const int*)d_in[5];
    const int*   hill  = (const int*)d_in[6];
    const void*  uses  = d_in[7];
    float* out = (float*)d_out;
    float* cfs = (float*)d_ws;

    sindy_prep<<<1, 256, 0, stream>>>(a, lin, drug, bilin, mm2, hill, uses, cfs);

    const int npts = out_size;                    // 128*2048 = 262144
    const int nblocks = npts / PTS_PER_BLOCK;     // 512
    sindy_main<<<nblocks, 256, 0, stream>>>(cand, cfs, out);
}